// Round 22
// baseline (36.807 us; speedup 1.0000x reference)
//
#include <hip/hip_runtime.h>
#include <math.h>

#define U 128
#define NIT 10   // 1-term Picard iters/layer + exact-W correction (validated R16-18,R21)

typedef __attribute__((ext_vector_type(8))) short bf16x8;
typedef __attribute__((ext_vector_type(4))) float f32x4;
typedef __attribute__((ext_vector_type(4))) unsigned int u32x4;

__device__ inline unsigned int pack2(float a, float b) {
    return (__float_as_uint(a) >> 16) | (__float_as_uint(b) & 0xFFFF0000u);
}
__device__ inline float lo_of(float a) {
    return a - __uint_as_float(__float_as_uint(a) & 0xFFFF0000u);
}
__device__ inline unsigned int packrn(float a, float b) {
    // RTNE pack (v_cvt_pk_bf16_f32)
    unsigned int r;
    asm("v_cvt_pk_bf16_f32 %0, %1, %2" : "=v"(r) : "v"(a), "v"(b));
    return r;
}
// R17/R18: f32 division = VCC-serialized; v_rcp_f32 pipelined, ~1 ULP.
__device__ inline float rcp_fast(float x) {
    float r;
    asm("v_rcp_f32 %0, %1" : "=v"(r) : "v"(x));
    return r;
}
__device__ inline float tanh_fast(float v) {
    float e = __expf(2.0f * v);
    return __builtin_fmaf(-2.0f, rcp_fast(e + 1.0f), 1.0f);
}
#define MFMA(A, B, C) __builtin_amdgcn_mfma_f32_16x16x32_bf16(A, B, C, 0, 0, 0)

#define SPLIT8(P4, Q4, H, LO)                                              \
{   u32x4 h_, l_;                                                          \
    h_[0] = pack2(P4.x, P4.y); h_[1] = pack2(P4.z, P4.w);                  \
    h_[2] = pack2(Q4.x, Q4.y); h_[3] = pack2(Q4.z, Q4.w);                  \
    l_[0] = pack2(lo_of(P4.x), lo_of(P4.y));                               \
    l_[1] = pack2(lo_of(P4.z), lo_of(P4.w));                               \
    l_[2] = pack2(lo_of(Q4.x), lo_of(Q4.y));                               \
    l_[3] = pack2(lo_of(Q4.z), lo_of(Q4.w));                               \
    H  = __builtin_bit_cast(bf16x8, h_);                                   \
    LO = __builtin_bit_cast(bf16x8, l_); }

// ---------------------------------------------------------------------------
// k_gemm_in: zA = X @ Wi^T + bi (f32). R10 version (measured 8.8us, R11).
// ---------------------------------------------------------------------------
__global__ __launch_bounds__(512) void k_gemm_in(
        const float* __restrict__ X, const float* __restrict__ Wi,
        const float* __restrict__ bi, float* __restrict__ zA) {
    __shared__ f32x4 redS[4][64];
    const int tid  = threadIdx.x;
    const int w    = tid >> 6;
    const int lane = tid & 63;
    const int l15  = lane & 15;
    const int lq   = lane >> 4;
    const int slab = blockIdx.x & 127;
    const int ch   = blockIdx.x >> 7;
    const int ct   = w & 3;
    const int kh   = w >> 2;
    const int r0   = slab * 16;
    const int cb   = ch * 64 + ct * 16;
    const int colA = cb + l15;
    const int KD   = 784;

    const float* xp = &X[(long)(r0 + l15) * KD];
    const float* wp = &Wi[(long)colA * KD];

    f32x4 a0 = {0.f, 0.f, 0.f, 0.f};
    f32x4 a1 = {0.f, 0.f, 0.f, 0.f};
    f32x4 a2 = {0.f, 0.f, 0.f, 0.f};
    if (kh == 0) {
        float4 b4 = *(const float4*)&bi[cb + lq * 4];
        a0[0] = b4.x; a0[1] = b4.y; a0[2] = b4.z; a0[3] = b4.w;
    }

    const int kbase = kh ? 384 : 0;
    #pragma unroll 6
    for (int c = 0; c < 12; ++c) {
        const int k = kbase + c * 32 + lq * 8;
        float4 xa = *(const float4*)&xp[k];
        float4 xb = *(const float4*)&xp[k + 4];
        float4 wa = *(const float4*)&wp[k];
        float4 wb = *(const float4*)&wp[k + 4];
        bf16x8 ah, al, bh, bl;
        SPLIT8(xa, xb, ah, al)
        SPLIT8(wa, wb, bh, bl)
        a0 = MFMA(bh, ah, a0);
        a1 = MFMA(bh, al, a1);
        a2 = MFMA(bl, ah, a2);
    }
    if (kh) {
        float4 z4 = make_float4(0.f, 0.f, 0.f, 0.f);
        float4 xa = z4, xb = z4, wa = z4, wb = z4;
        if (lq < 2) {
            const int k = 768 + lq * 8;
            xa = *(const float4*)&xp[k];
            xb = *(const float4*)&xp[k + 4];
            wa = *(const float4*)&wp[k];
            wb = *(const float4*)&wp[k + 4];
        }
        bf16x8 ah, al, bh, bl;
        SPLIT8(xa, xb, ah, al)
        SPLIT8(wa, wb, bh, bl)
        a0 = MFMA(bh, ah, a0);
        a1 = MFMA(bh, al, a1);
        a2 = MFMA(bl, ah, a2);
    }

    f32x4 r;
    #pragma unroll
    for (int i = 0; i < 4; ++i) r[i] = a0[i] + a1[i] + a2[i];

    if (kh) redS[ct][lane] = r;
    __syncthreads();
    if (!kh) {
        f32x4 o = redS[ct][lane];
        float4 st;
        st.x = r[0] + o[0]; st.y = r[1] + o[1];
        st.z = r[2] + o[2]; st.w = r[3] + o[3];
        *(float4*)&zA[(long)(r0 + l15) * U + cb + lq * 4] = st;
    }
}

// ---------------------------------------------------------------------------
// k_picard: TWO independent 16-row tiles PER WAVE (within-wave ILP).
// grid = B/32 blocks, 256 threads (4 waves). Wave w owns cols 32w..32w+31 of
// BOTH tile0 (rows r0..r0+15) and tile1 (rows r0+16..r0+31): two independent
// dependency chains interleave in one instruction stream; the barrier stays
// 4-wave (R20's 8-wave coupling avoided); W registers shared between tiles.
// In-loop W = 1-term RTNE bf16 + one exact-W (JIT lo) correction per layer
// (numerics validated R16-18/R21, absmax 1.953e-3). rcp-tanh throughout.
// LDS z per tile: byte(r,c) = r*256 + ((2c)^((r&7)<<4)); [tile][buf] regions.
// Phase 3: waves 0,1 each output one tile via 3-term MFMA + shuffle softmax.
// ---------------------------------------------------------------------------
__global__ __launch_bounds__(256) void k_picard(
        const float* __restrict__ zA, const float* __restrict__ Wb,
        const float* __restrict__ Wo, const float* __restrict__ bo,
        float* __restrict__ Out, int L) {
    __shared__ unsigned short zhS[2][2][16 * U];   // [tile][buf] = 16 KB

    const int tid  = threadIdx.x;
    const int w    = tid >> 6;          // 0..3
    const int lane = tid & 63;
    const int l15  = lane & 15;
    const int lq   = lane >> 4;
    const int r0   = blockIdx.x * 32;

    // x (z-lin) for both tiles: lane l15 = batch row
    float xf0[8], xf1[8], zr[8];
    {
        const float* zr0 = &zA[(long)(r0 + l15) * U + w * 32 + lq * 4];
        const float* zr1 = &zA[(long)(r0 + 16 + l15) * U + w * 32 + lq * 4];
        float4 a = *(const float4*)&zr0[0];
        float4 b = *(const float4*)&zr0[16];
        float4 c = *(const float4*)&zr1[0];
        float4 d = *(const float4*)&zr1[16];
        xf0[0]=a.x; xf0[1]=a.y; xf0[2]=a.z; xf0[3]=a.w;
        xf0[4]=b.x; xf0[5]=b.y; xf0[6]=b.z; xf0[7]=b.w;
        xf1[0]=c.x; xf1[1]=c.y; xf1[2]=c.z; xf1[3]=c.w;
        xf1[4]=d.x; xf1[5]=d.y; xf1[6]=d.z; xf1[7]=d.w;
    }

    const int swz = (l15 & 7) << 4;
    int offA[4];
    #pragma unroll
    for (int ks = 0; ks < 4; ++ks)
        offA[ks] = l15 * 256 + ((64 * ks + 16 * lq) ^ swz);
    const int offW0 = l15 * 256 + (((64 * w + 8 * lq)) ^ swz);
    const int offW1 = l15 * 256 + (((64 * w + 32 + 8 * lq)) ^ swz);

    char* zB0 = (char*)&zhS[0][0][0];   // tile0 (buf stride 4096)
    char* zB1 = (char*)&zhS[1][0][0];   // tile1

    for (int l = 0; l < L; ++l) {
        // layer weights, 1-term RTNE bf16 -- SHARED by both tiles (same cols)
        bf16x8 whf[2][4];
        #pragma unroll
        for (int ct = 0; ct < 2; ++ct) {
            const int colA = w * 32 + ct * 16 + l15;
            const float* wrow = &Wb[((long)l * U + colA) * U];
            #pragma unroll
            for (int ks = 0; ks < 4; ++ks) {
                const int k = ks * 32 + lq * 8;
                float4 p = *(const float4*)&wrow[k];
                float4 q = *(const float4*)&wrow[k + 4];
                u32x4 h;
                h[0] = packrn(p.x, p.y); h[1] = packrn(p.z, p.w);
                h[2] = packrn(q.x, q.y); h[3] = packrn(q.z, q.w);
                whf[ct][ks] = __builtin_bit_cast(bf16x8, h);
            }
        }

        // z0 = tanh(x) -> buf0 of each tile
        {
            uint2 h0, h1;
            #pragma unroll
            for (int i = 0; i < 8; ++i) zr[i] = tanh_fast(xf0[i]);
            h0.x = packrn(zr[0], zr[1]); h0.y = packrn(zr[2], zr[3]);
            h1.x = packrn(zr[4], zr[5]); h1.y = packrn(zr[6], zr[7]);
            *(uint2*)(zB0 + offW0) = h0;
            *(uint2*)(zB0 + offW1) = h1;
            #pragma unroll
            for (int i = 0; i < 8; ++i) zr[i] = tanh_fast(xf1[i]);
            h0.x = packrn(zr[0], zr[1]); h0.y = packrn(zr[2], zr[3]);
            h1.x = packrn(zr[4], zr[5]); h1.y = packrn(zr[6], zr[7]);
            *(uint2*)(zB1 + offW0) = h0;
            *(uint2*)(zB1 + offW1) = h1;
        }
        __syncthreads();

        // NIT rounds; both tiles advance per round (independent chains)
        #pragma unroll 2
        for (int it = 0; it < NIT; ++it) {
            const int cur = it & 1;
            const int nxt = cur ^ 1;
            bf16x8 z0f[4], z1f[4];
            #pragma unroll
            for (int ks = 0; ks < 4; ++ks) {
                z0f[ks] = *(const bf16x8*)(zB0 + cur * 4096 + offA[ks]);
                z1f[ks] = *(const bf16x8*)(zB1 + cur * 4096 + offA[ks]);
            }

            f32x4 Z4 = {0.f, 0.f, 0.f, 0.f};
            f32x4 A0 = {xf0[0], xf0[1], xf0[2], xf0[3]};
            f32x4 A1 = Z4;
            f32x4 B0 = {xf0[4], xf0[5], xf0[6], xf0[7]};
            f32x4 B1 = Z4;
            f32x4 C0 = {xf1[0], xf1[1], xf1[2], xf1[3]};
            f32x4 C1 = Z4;
            f32x4 D0 = {xf1[4], xf1[5], xf1[6], xf1[7]};
            f32x4 D1 = Z4;
            A0 = MFMA(whf[0][0], z0f[0], A0);
            C0 = MFMA(whf[0][0], z1f[0], C0);
            B0 = MFMA(whf[1][0], z0f[0], B0);
            D0 = MFMA(whf[1][0], z1f[0], D0);
            A1 = MFMA(whf[0][2], z0f[2], A1);
            C1 = MFMA(whf[0][2], z1f[2], C1);
            B1 = MFMA(whf[1][2], z0f[2], B1);
            D1 = MFMA(whf[1][2], z1f[2], D1);
            A0 = MFMA(whf[0][1], z0f[1], A0);
            C0 = MFMA(whf[0][1], z1f[1], C0);
            B0 = MFMA(whf[1][1], z0f[1], B0);
            D0 = MFMA(whf[1][1], z1f[1], D0);
            A1 = MFMA(whf[0][3], z0f[3], A1);
            C1 = MFMA(whf[0][3], z1f[3], C1);
            B1 = MFMA(whf[1][3], z0f[3], B1);
            D1 = MFMA(whf[1][3], z1f[3], D1);

            uint2 h0, h1;
            #pragma unroll
            for (int i = 0; i < 4; ++i) {
                zr[i]     = tanh_fast(A0[i] + A1[i]);
                zr[4 + i] = tanh_fast(B0[i] + B1[i]);
            }
            h0.x = packrn(zr[0], zr[1]); h0.y = packrn(zr[2], zr[3]);
            h1.x = packrn(zr[4], zr[5]); h1.y = packrn(zr[6], zr[7]);
            *(uint2*)(zB0 + nxt * 4096 + offW0) = h0;
            *(uint2*)(zB0 + nxt * 4096 + offW1) = h1;
            #pragma unroll
            for (int i = 0; i < 4; ++i) {
                zr[i]     = tanh_fast(C0[i] + C1[i]);
                zr[4 + i] = tanh_fast(D0[i] + D1[i]);
            }
            h0.x = packrn(zr[0], zr[1]); h0.y = packrn(zr[2], zr[3]);
            h1.x = packrn(zr[4], zr[5]); h1.y = packrn(zr[6], zr[7]);
            *(uint2*)(zB1 + nxt * 4096 + offW0) = h0;
            *(uint2*)(zB1 + nxt * 4096 + offW1) = h1;
            __syncthreads();
        }

        // Exact-W correction (JIT W-lo), both tiles; z-hi in buf0 (NIT even).
        {
            bf16x8 z0f[4], z1f[4];
            #pragma unroll
            for (int ks = 0; ks < 4; ++ks) {
                z0f[ks] = *(const bf16x8*)(zB0 + offA[ks]);
                z1f[ks] = *(const bf16x8*)(zB1 + offA[ks]);
            }
            #pragma unroll
            for (int ct = 0; ct < 2; ++ct) {
                const int colA = w * 32 + ct * 16 + l15;
                const float* wrow = &Wb[((long)l * U + colA) * U];
                f32x4 dH0 = {xf0[ct*4+0], xf0[ct*4+1], xf0[ct*4+2], xf0[ct*4+3]};
                f32x4 dH1 = {xf1[ct*4+0], xf1[ct*4+1], xf1[ct*4+2], xf1[ct*4+3]};
                f32x4 dL0 = {0.f, 0.f, 0.f, 0.f};
                f32x4 dL1 = dL0;
                #pragma unroll
                for (int ks = 0; ks < 4; ++ks) {
                    const float* wp = &wrow[32 * ks + 8 * lq];
                    float4 p = *(const float4*)&wp[0];
                    float4 q = *(const float4*)&wp[4];
                    u32x4 h = __builtin_bit_cast(u32x4, whf[ct][ks]);
                    float lo0 = p.x - __uint_as_float(h[0] << 16);
                    float lo1 = p.y - __uint_as_float(h[0] & 0xFFFF0000u);
                    float lo2 = p.z - __uint_as_float(h[1] << 16);
                    float lo3 = p.w - __uint_as_float(h[1] & 0xFFFF0000u);
                    float lo4 = q.x - __uint_as_float(h[2] << 16);
                    float lo5 = q.y - __uint_as_float(h[2] & 0xFFFF0000u);
                    float lo6 = q.z - __uint_as_float(h[3] << 16);
                    float lo7 = q.w - __uint_as_float(h[3] & 0xFFFF0000u);
                    u32x4 lw;
                    lw[0] = packrn(lo0, lo1); lw[1] = packrn(lo2, lo3);
                    lw[2] = packrn(lo4, lo5); lw[3] = packrn(lo6, lo7);
                    bf16x8 wlf = __builtin_bit_cast(bf16x8, lw);
                    dH0 = MFMA(whf[ct][ks], z0f[ks], dH0);
                    dH1 = MFMA(whf[ct][ks], z1f[ks], dH1);
                    dL0 = MFMA(wlf, z0f[ks], dL0);
                    dL1 = MFMA(wlf, z1f[ks], dL1);
                }
                #pragma unroll
                for (int i = 0; i < 4; ++i) {
                    xf0[ct*4+i] = tanh_fast(dH0[i] + dL0[i]);
                    xf1[ct*4+i] = tanh_fast(dH1[i] + dL1[i]);
                }
            }
        }
        __syncthreads();
    }

    // Final z* -> buf0 hi + buf1 lo per tile (3-term output GEMM)
    {
        #pragma unroll
        for (int t = 0; t < 2; ++t) {
            const float* xs = t ? xf1 : xf0;
            char* zb = t ? zB1 : zB0;
            unsigned int h0 = packrn(xs[0], xs[1]);
            unsigned int h1 = packrn(xs[2], xs[3]);
            unsigned int h2 = packrn(xs[4], xs[5]);
            unsigned int h3 = packrn(xs[6], xs[7]);
            uint2 H0, H1, L0, L1;
            H0.x = h0; H0.y = h1; H1.x = h2; H1.y = h3;
            L0.x = packrn(xs[0] - __uint_as_float(h0 << 16),
                          xs[1] - __uint_as_float(h0 & 0xFFFF0000u));
            L0.y = packrn(xs[2] - __uint_as_float(h1 << 16),
                          xs[3] - __uint_as_float(h1 & 0xFFFF0000u));
            L1.x = packrn(xs[4] - __uint_as_float(h2 << 16),
                          xs[5] - __uint_as_float(h2 & 0xFFFF0000u));
            L1.y = packrn(xs[6] - __uint_as_float(h3 << 16),
                          xs[7] - __uint_as_float(h3 & 0xFFFF0000u));
            *(uint2*)(zb + offW0) = H0;
            *(uint2*)(zb + offW1) = H1;
            *(uint2*)(zb + 4096 + offW0) = L0;
            *(uint2*)(zb + 4096 + offW1) = L1;
        }
    }
    __syncthreads();

    // --------- Phase 3 (waves 0,1 -> tile w): softmax(z @ Wo^T + bo) -------
    if (w < 2) {
        char* zb = w ? zB1 : zB0;
        bf16x8 woh[4], wol[4];
        #pragma unroll
        for (int ks = 0; ks < 4; ++ks) {
            float4 p = make_float4(0.f, 0.f, 0.f, 0.f), q = p;
            if (l15 < 10) {
                const float* worow = &Wo[l15 * U + ks * 32 + lq * 8];
                p = *(const float4*)&worow[0];
                q = *(const float4*)&worow[4];
            }
            SPLIT8(p, q, woh[ks], wol[ks])
        }
        bf16x8 zf[4], zl[4];
        #pragma unroll
        for (int ks = 0; ks < 4; ++ks) {
            zf[ks] = *(const bf16x8*)(zb + offA[ks]);
            zl[ks] = *(const bf16x8*)(zb + 4096 + offA[ks]);
        }

        f32x4 d0 = {0.f, 0.f, 0.f, 0.f};
        f32x4 d1 = d0, d2 = d0;
        #pragma unroll
        for (int ks = 0; ks < 4; ++ks) {
            d0 = MFMA(woh[ks], zf[ks], d0);
            d1 = MFMA(wol[ks], zf[ks], d1);
            d2 = MFMA(woh[ks], zl[ks], d2);
        }
        float lg[4];
        #pragma unroll
        for (int i = 0; i < 4; ++i) {
            const int c = 4 * lq + i;
            lg[i] = (c < 10) ? (d0[i] + d1[i] + d2[i] + bo[c]) : -1e30f;
        }
        float m = fmaxf(fmaxf(lg[0], lg[1]), fmaxf(lg[2], lg[3]));
        m = fmaxf(m, __shfl_xor(m, 16));
        m = fmaxf(m, __shfl_xor(m, 32));
        float e[4], s = 0.f;
        #pragma unroll
        for (int i = 0; i < 4; ++i) { e[i] = __expf(lg[i] - m); s += e[i]; }
        s += __shfl_xor(s, 16);
        s += __shfl_xor(s, 32);
        const float inv = rcp_fast(s);
        const float inv2 = inv * (2.0f - s * inv);
        #pragma unroll
        for (int i = 0; i < 4; ++i) {
            const int c = 4 * lq + i;
            if (c < 10) Out[(long)(r0 + w * 16 + l15) * 10 + c] = e[i] * inv2;
        }
    }
}

// ---------------------------------------------------------------------------
extern "C" void kernel_launch(void* const* d_in, const int* in_sizes, int n_in,
                              void* d_out, int out_size, void* d_ws, size_t ws_size,
                              hipStream_t stream) {
    const float* x  = (const float*)d_in[0];   // [B,784]
    const float* Wi = (const float*)d_in[1];   // [128,784]
    const float* bi = (const float*)d_in[2];   // [128]
    const float* Wb = (const float*)d_in[3];   // [L,128,128]
    const float* Wo = (const float*)d_in[4];   // [10,128]
    const float* bo = (const float*)d_in[5];   // [10]
    float* out = (float*)d_out;

    const int DIN = 784;
    const int B   = in_sizes[0] / DIN;             // 2048
    const int L   = in_sizes[3] / (U * U);         // 2

    float* zA = (float*)d_ws;                      // [B,U] f32

    k_gemm_in<<<256, 512, 0, stream>>>(x, Wi, bi, zA);
    k_picard<<<B / 32, 256, 0, stream>>>(zA, Wb, Wo, bo, out, L);
}

// Round 23
// 27.630 us; speedup vs baseline: 1.3321x; 1.3321x over previous
//
#include <hip/hip_runtime.h>
#include <math.h>

#define U 128
#define NIT 8    // even; rho <= ~0.45 (absmax pinned at quant floor for NIT>=10
                 // across {10,12,16,20,48}) -> iter err ~5e-4 < 2e-3 floor

typedef __attribute__((ext_vector_type(8))) short bf16x8;
typedef __attribute__((ext_vector_type(4))) float f32x4;
typedef __attribute__((ext_vector_type(4))) unsigned int u32x4;

__device__ inline unsigned int pack2(float a, float b) {
    return (__float_as_uint(a) >> 16) | (__float_as_uint(b) & 0xFFFF0000u);
}
__device__ inline float lo_of(float a) {
    return a - __uint_as_float(__float_as_uint(a) & 0xFFFF0000u);
}
__device__ inline unsigned int packrn(float a, float b) {
    unsigned int r;
    asm("v_cvt_pk_bf16_f32 %0, %1, %2" : "=v"(r) : "v"(a), "v"(b));
    return r;
}
__device__ inline float fromhi(unsigned short h) {
    return __uint_as_float(((unsigned int)h) << 16);
}
// f32 division = VCC-serialized div_scale/div_fmas/div_fixup; v_rcp_f32 is
// pipelined, ~1 ULP (validated R18/R19: absmax bit-identical).
__device__ inline float rcp_fast(float x) {
    float r;
    asm("v_rcp_f32 %0, %1" : "=v"(r) : "v"(x));
    return r;
}
__device__ inline float tanh_fast(float v) {
    float e = __expf(2.0f * v);
    return __builtin_fmaf(-2.0f, rcp_fast(e + 1.0f), 1.0f);
}
#define MFMA(A, B, C) __builtin_amdgcn_mfma_f32_16x16x32_bf16(A, B, C, 0, 0, 0)

#define SPLIT8(P4, Q4, H, LO)                                              \
{   u32x4 h_, l_;                                                          \
    h_[0] = pack2(P4.x, P4.y); h_[1] = pack2(P4.z, P4.w);                  \
    h_[2] = pack2(Q4.x, Q4.y); h_[3] = pack2(Q4.z, Q4.w);                  \
    l_[0] = pack2(lo_of(P4.x), lo_of(P4.y));                               \
    l_[1] = pack2(lo_of(P4.z), lo_of(P4.w));                               \
    l_[2] = pack2(lo_of(Q4.x), lo_of(Q4.y));                               \
    l_[3] = pack2(lo_of(Q4.z), lo_of(Q4.w));                               \
    H  = __builtin_bit_cast(bf16x8, h_);                                   \
    LO = __builtin_bit_cast(bf16x8, l_); }

// ---------------------------------------------------------------------------
// k_gemm_in v3: R10 mapping (256 blocks, 8 waves, split-K=2) with EXPLICIT
// staged loads (3 groups of 4 chunks, 2-deep software pipeline) to force
// load batching -- the unroll-6 version compiled to minimal VGPR and
// serialized its global loads (8.8us at 1.3% HBM = latency-bound).
// ---------------------------------------------------------------------------
__global__ __launch_bounds__(512) void k_gemm_in(
        const float* __restrict__ X, const float* __restrict__ Wi,
        const float* __restrict__ bi, float* __restrict__ zA) {
    __shared__ f32x4 redS[4][64];
    const int tid  = threadIdx.x;
    const int w    = tid >> 6;
    const int lane = tid & 63;
    const int l15  = lane & 15;
    const int lq   = lane >> 4;
    const int slab = blockIdx.x & 127;
    const int ch   = blockIdx.x >> 7;
    const int ct   = w & 3;
    const int kh   = w >> 2;
    const int r0   = slab * 16;
    const int cb   = ch * 64 + ct * 16;
    const int colA = cb + l15;
    const int KD   = 784;

    const float* xp = &X[(long)(r0 + l15) * KD];
    const float* wp = &Wi[(long)colA * KD];

    f32x4 a0 = {0.f, 0.f, 0.f, 0.f};
    f32x4 a1 = {0.f, 0.f, 0.f, 0.f};
    f32x4 a2 = {0.f, 0.f, 0.f, 0.f};
    if (kh == 0) {
        float4 b4 = *(const float4*)&bi[cb + lq * 4];
        a0[0] = b4.x; a0[1] = b4.y; a0[2] = b4.z; a0[3] = b4.w;
    }

    const int kbase = kh ? 384 : 0;
    float4 s0[4][4], s1[4][4];

    #define LOADG(S, CBASE)                                                \
    {   _Pragma("unroll")                                                  \
        for (int c = 0; c < 4; ++c) {                                      \
            const int k = kbase + (CBASE + c) * 32 + lq * 8;               \
            S[c][0] = *(const float4*)&xp[k];                              \
            S[c][1] = *(const float4*)&xp[k + 4];                          \
            S[c][2] = *(const float4*)&wp[k];                              \
            S[c][3] = *(const float4*)&wp[k + 4];                          \
        } }
    #define CONSG(S)                                                       \
    {   _Pragma("unroll")                                                  \
        for (int c = 0; c < 4; ++c) {                                      \
            bf16x8 ah, al, bh, bl;                                         \
            SPLIT8(S[c][0], S[c][1], ah, al)                               \
            SPLIT8(S[c][2], S[c][3], bh, bl)                               \
            a0 = MFMA(bh, ah, a0);                                         \
            a1 = MFMA(bh, al, a1);                                         \
            a2 = MFMA(bl, ah, a2);                                         \
        } }

    LOADG(s0, 0)
    LOADG(s1, 4)
    CONSG(s0)
    LOADG(s0, 8)
    CONSG(s1)
    CONSG(s0)
    #undef LOADG
    #undef CONSG

    if (kh) {   // tail k = 768..783 (valid lq<2)
        float4 z4 = make_float4(0.f, 0.f, 0.f, 0.f);
        float4 xa = z4, xb = z4, wa = z4, wb = z4;
        if (lq < 2) {
            const int k = 768 + lq * 8;
            xa = *(const float4*)&xp[k];
            xb = *(const float4*)&xp[k + 4];
            wa = *(const float4*)&wp[k];
            wb = *(const float4*)&wp[k + 4];
        }
        bf16x8 ah, al, bh, bl;
        SPLIT8(xa, xb, ah, al)
        SPLIT8(wa, wb, bh, bl)
        a0 = MFMA(bh, ah, a0);
        a1 = MFMA(bh, al, a1);
        a2 = MFMA(bl, ah, a2);
    }

    f32x4 r;
    #pragma unroll
    for (int i = 0; i < 4; ++i) r[i] = a0[i] + a1[i] + a2[i];

    if (kh) redS[ct][lane] = r;
    __syncthreads();
    if (!kh) {
        f32x4 o = redS[ct][lane];
        float4 st;
        st.x = r[0] + o[0]; st.y = r[1] + o[1];
        st.z = r[2] + o[2]; st.w = r[3] + o[3];
        *(float4*)&zA[(long)(r0 + l15) * U + cb + lq * 4] = st;
    }
}

// ---------------------------------------------------------------------------
// k_picard: EXACT R19 structure (best measured: 29.3us total) -- 4 waves x
// 2 col-tiles, 3-term W in registers, bf16-hi LDS ping-pong, rcp-tanh,
// final z hi+lo -> 3-term output GEMM on wave 0. Only change: NIT 10 -> 8.
// LDS z: byte(r,c) = r*256 + ((2c) ^ ((r&7)<<4))  XOR swizzle.
// ---------------------------------------------------------------------------
__global__ __launch_bounds__(256) void k_picard(
        const float* __restrict__ zA, const float* __restrict__ Wb,
        const float* __restrict__ Wo, const float* __restrict__ bo,
        float* __restrict__ Out, int L) {
    __shared__ unsigned short zhS[2][16 * U];   // 2 x 4 KB (dbuf; buf1 = z_lo at end)

    const int tid  = threadIdx.x;
    const int w    = tid >> 6;          // 0..3
    const int lane = tid & 63;
    const int l15  = lane & 15;
    const int lq   = lane >> 4;
    const int r0   = blockIdx.x * 16;

    float xf[8], zr[8];
    {
        const float* zrow = &zA[(long)(r0 + l15) * U + w * 32 + lq * 4];
        float4 x40 = *(const float4*)&zrow[0];
        float4 x41 = *(const float4*)&zrow[16];
        xf[0] = x40.x; xf[1] = x40.y; xf[2] = x40.z; xf[3] = x40.w;
        xf[4] = x41.x; xf[5] = x41.y; xf[6] = x41.z; xf[7] = x41.w;
    }

    const int swz = (l15 & 7) << 4;
    int offA[4];
    #pragma unroll
    for (int ks = 0; ks < 4; ++ks)
        offA[ks] = l15 * 256 + ((64 * ks + 16 * lq) ^ swz);
    const int offW0 = l15 * 256 + (((64 * w + 8 * lq)) ^ swz);
    const int offW1 = l15 * 256 + (((64 * w + 32 + 8 * lq)) ^ swz);

    char* zhB = (char*)&zhS[0][0];

    for (int l = 0; l < L; ++l) {
        bf16x8 whf[2][4], wlf[2][4];
        #pragma unroll
        for (int ct = 0; ct < 2; ++ct) {
            const int colA = w * 32 + ct * 16 + l15;
            const float* wrow = &Wb[((long)l * U + colA) * U];
            #pragma unroll
            for (int ks = 0; ks < 4; ++ks) {
                const int k = ks * 32 + lq * 8;
                float4 p = *(const float4*)&wrow[k];
                float4 q = *(const float4*)&wrow[k + 4];
                SPLIT8(p, q, whf[ct][ks], wlf[ct][ks])
            }
        }

        {
            uint2 h0, h1;
            #pragma unroll
            for (int i = 0; i < 8; ++i) zr[i] = tanh_fast(xf[i]);
            h0.x = packrn(zr[0], zr[1]); h0.y = packrn(zr[2], zr[3]);
            h1.x = packrn(zr[4], zr[5]); h1.y = packrn(zr[6], zr[7]);
            *(uint2*)(zhB + offW0) = h0;
            *(uint2*)(zhB + offW1) = h1;
        }
        __syncthreads();

        #pragma unroll 2
        for (int it = 0; it < NIT; ++it) {
            const int cur = it & 1;
            const int nxt = cur ^ 1;
            bf16x8 zhf[4];
            #pragma unroll
            for (int ks = 0; ks < 4; ++ks)
                zhf[ks] = *(const bf16x8*)(zhB + cur * 4096 + offA[ks]);

            f32x4 A0 = {xf[0], xf[1], xf[2], xf[3]};
            f32x4 Z4 = {0.f, 0.f, 0.f, 0.f};
            f32x4 A1 = Z4, A2 = Z4, A3 = Z4;
            f32x4 B0 = {xf[4], xf[5], xf[6], xf[7]};
            f32x4 B1 = Z4, B2 = Z4, B3 = Z4;
            A0 = MFMA(whf[0][0], zhf[0], A0);
            B0 = MFMA(whf[1][0], zhf[0], B0);
            A1 = MFMA(whf[0][2], zhf[2], A1);
            B1 = MFMA(whf[1][2], zhf[2], B1);
            A2 = MFMA(wlf[0][0], zhf[0], A2);
            B2 = MFMA(wlf[1][0], zhf[0], B2);
            A3 = MFMA(wlf[0][2], zhf[2], A3);
            B3 = MFMA(wlf[1][2], zhf[2], B3);
            A0 = MFMA(whf[0][1], zhf[1], A0);
            B0 = MFMA(whf[1][1], zhf[1], B0);
            A1 = MFMA(whf[0][3], zhf[3], A1);
            B1 = MFMA(whf[1][3], zhf[3], B1);
            A2 = MFMA(wlf[0][1], zhf[1], A2);
            B2 = MFMA(wlf[1][1], zhf[1], B2);
            A3 = MFMA(wlf[0][3], zhf[3], A3);
            B3 = MFMA(wlf[1][3], zhf[3], B3);

            #pragma unroll
            for (int i = 0; i < 4; ++i) {
                zr[i]     = tanh_fast(A0[i] + A1[i] + A2[i] + A3[i]);
                zr[4 + i] = tanh_fast(B0[i] + B1[i] + B2[i] + B3[i]);
            }
            uint2 h0, h1;
            h0.x = packrn(zr[0], zr[1]); h0.y = packrn(zr[2], zr[3]);
            h1.x = packrn(zr[4], zr[5]); h1.y = packrn(zr[6], zr[7]);
            *(uint2*)(zhB + nxt * 4096 + offW0) = h0;
            *(uint2*)(zhB + nxt * 4096 + offW1) = h1;
            __syncthreads();
        }
        #pragma unroll
        for (int i = 0; i < 8; ++i) xf[i] = zr[i];
    }
    // NIT even => final z hi in buffer 0; z_lo -> buffer 1 (3-term phase 3)
    {
        uint2 l0, l1;
        l0.x = packrn(zr[0] - fromhi((unsigned short)(packrn(zr[0], zr[0]))),
                      zr[1] - fromhi((unsigned short)(packrn(zr[1], zr[1]))));
        l0.y = packrn(zr[2] - fromhi((unsigned short)(packrn(zr[2], zr[2]))),
                      zr[3] - fromhi((unsigned short)(packrn(zr[3], zr[3]))));
        l1.x = packrn(zr[4] - fromhi((unsigned short)(packrn(zr[4], zr[4]))),
                      zr[5] - fromhi((unsigned short)(packrn(zr[5], zr[5]))));
        l1.y = packrn(zr[6] - fromhi((unsigned short)(packrn(zr[6], zr[6]))),
                      zr[7] - fromhi((unsigned short)(packrn(zr[7], zr[7]))));
        *(uint2*)(zhB + 4096 + offW0) = l0;
        *(uint2*)(zhB + 4096 + offW1) = l1;
    }
    __syncthreads();

    if (w == 0) {
        bf16x8 woh[4], wol[4];
        #pragma unroll
        for (int ks = 0; ks < 4; ++ks) {
            float4 p = make_float4(0.f, 0.f, 0.f, 0.f), q = p;
            if (l15 < 10) {
                const float* worow = &Wo[l15 * U + ks * 32 + lq * 8];
                p = *(const float4*)&worow[0];
                q = *(const float4*)&worow[4];
            }
            SPLIT8(p, q, woh[ks], wol[ks])
        }
        bf16x8 zf[4], zl[4];
        #pragma unroll
        for (int ks = 0; ks < 4; ++ks) {
            zf[ks] = *(const bf16x8*)(zhB + offA[ks]);
            zl[ks] = *(const bf16x8*)(zhB + 4096 + offA[ks]);
        }

        f32x4 d0 = {0.f, 0.f, 0.f, 0.f};
        f32x4 d1 = d0, d2 = d0;
        #pragma unroll
        for (int ks = 0; ks < 4; ++ks) {
            d0 = MFMA(woh[ks], zf[ks], d0);
            d1 = MFMA(wol[ks], zf[ks], d1);
            d2 = MFMA(woh[ks], zl[ks], d2);
        }
        float lg[4];
        #pragma unroll
        for (int i = 0; i < 4; ++i) {
            const int c = 4 * lq + i;
            lg[i] = (c < 10) ? (d0[i] + d1[i] + d2[i] + bo[c]) : -1e30f;
        }
        float m = fmaxf(fmaxf(lg[0], lg[1]), fmaxf(lg[2], lg[3]));
        m = fmaxf(m, __shfl_xor(m, 16));
        m = fmaxf(m, __shfl_xor(m, 32));
        float e[4], s = 0.f;
        #pragma unroll
        for (int i = 0; i < 4; ++i) { e[i] = __expf(lg[i] - m); s += e[i]; }
        s += __shfl_xor(s, 16);
        s += __shfl_xor(s, 32);
        const float inv = rcp_fast(s);
        const float inv2 = inv * (2.0f - s * inv);
        #pragma unroll
        for (int i = 0; i < 4; ++i) {
            const int c = 4 * lq + i;
            if (c < 10) Out[(long)(r0 + l15) * 10 + c] = e[i] * inv2;
        }
    }
}

// ---------------------------------------------------------------------------
extern "C" void kernel_launch(void* const* d_in, const int* in_sizes, int n_in,
                              void* d_out, int out_size, void* d_ws, size_t ws_size,
                              hipStream_t stream) {
    const float* x  = (const float*)d_in[0];   // [B,784]
    const float* Wi = (const float*)d_in[1];   // [128,784]
    const float* bi = (const float*)d_in[2];   // [128]
    const float* Wb = (const float*)d_in[3];   // [L,128,128]
    const float* Wo = (const float*)d_in[4];   // [10,128]
    const float* bo = (const float*)d_in[5];   // [10]
    float* out = (float*)d_out;

    const int DIN = 784;
    const int B   = in_sizes[0] / DIN;             // 2048
    const int L   = in_sizes[3] / (U * U);         // 2

    float* zA = (float*)d_ws;                      // [B,U] f32

    k_gemm_in<<<256, 512, 0, stream>>>(x, Wi, bi, zA);
    k_picard<<<B / 16, 256, 0, stream>>>(zA, Wb, Wo, bo, out, L);
}

// Round 24
// 25.938 us; speedup vs baseline: 1.4191x; 1.0652x over previous
//
#include <hip/hip_runtime.h>
#include <math.h>

#define U 128
#define NIT 6    // even; absmax pinned at bf16 quant floor for all NIT>=8
                 // (8,10,12,16,20,48 all bit-identical) => rho^8*err0 << ulp;
                 // NIT=6 leaves ~1e-3 iter error, well under 9.7e-3 threshold

typedef __attribute__((ext_vector_type(8))) short bf16x8;
typedef __attribute__((ext_vector_type(4))) float f32x4;
typedef __attribute__((ext_vector_type(4))) unsigned int u32x4;

__device__ inline unsigned int pack2(float a, float b) {
    return (__float_as_uint(a) >> 16) | (__float_as_uint(b) & 0xFFFF0000u);
}
__device__ inline float lo_of(float a) {
    return a - __uint_as_float(__float_as_uint(a) & 0xFFFF0000u);
}
__device__ inline unsigned int packrn(float a, float b) {
    unsigned int r;
    asm("v_cvt_pk_bf16_f32 %0, %1, %2" : "=v"(r) : "v"(a), "v"(b));
    return r;
}
__device__ inline float fromhi(unsigned short h) {
    return __uint_as_float(((unsigned int)h) << 16);
}
// f32 division = VCC-serialized; v_rcp_f32 pipelined, ~1 ULP (validated).
__device__ inline float rcp_fast(float x) {
    float r;
    asm("v_rcp_f32 %0, %1" : "=v"(r) : "v"(x));
    return r;
}
__device__ inline float tanh_fast(float v) {
    float e = __expf(2.0f * v);
    return __builtin_fmaf(-2.0f, rcp_fast(e + 1.0f), 1.0f);
}
#define MFMA(A, B, C) __builtin_amdgcn_mfma_f32_16x16x32_bf16(A, B, C, 0, 0, 0)

#define SPLIT8(P4, Q4, H, LO)                                              \
{   u32x4 h_, l_;                                                          \
    h_[0] = pack2(P4.x, P4.y); h_[1] = pack2(P4.z, P4.w);                  \
    h_[2] = pack2(Q4.x, Q4.y); h_[3] = pack2(Q4.z, Q4.w);                  \
    l_[0] = pack2(lo_of(P4.x), lo_of(P4.y));                               \
    l_[1] = pack2(lo_of(P4.z), lo_of(P4.w));                               \
    l_[2] = pack2(lo_of(Q4.x), lo_of(Q4.y));                               \
    l_[3] = pack2(lo_of(Q4.z), lo_of(Q4.w));                               \
    H  = __builtin_bit_cast(bf16x8, h_);                                   \
    LO = __builtin_bit_cast(bf16x8, l_); }

// ---------------------------------------------------------------------------
// k_gemm_in: zA = X @ Wi^T + bi (f32). EXACT R10 version (measured 8.8us via
// R11 duplicate-launch). R22's explicit staging variant regressed (~+2us,
// inferred from R23's delta accounting) -- reverted.
// ---------------------------------------------------------------------------
__global__ __launch_bounds__(512) void k_gemm_in(
        const float* __restrict__ X, const float* __restrict__ Wi,
        const float* __restrict__ bi, float* __restrict__ zA) {
    __shared__ f32x4 redS[4][64];
    const int tid  = threadIdx.x;
    const int w    = tid >> 6;
    const int lane = tid & 63;
    const int l15  = lane & 15;
    const int lq   = lane >> 4;
    const int slab = blockIdx.x & 127;
    const int ch   = blockIdx.x >> 7;
    const int ct   = w & 3;
    const int kh   = w >> 2;
    const int r0   = slab * 16;
    const int cb   = ch * 64 + ct * 16;
    const int colA = cb + l15;
    const int KD   = 784;

    const float* xp = &X[(long)(r0 + l15) * KD];
    const float* wp = &Wi[(long)colA * KD];

    f32x4 a0 = {0.f, 0.f, 0.f, 0.f};
    f32x4 a1 = {0.f, 0.f, 0.f, 0.f};
    f32x4 a2 = {0.f, 0.f, 0.f, 0.f};
    if (kh == 0) {
        float4 b4 = *(const float4*)&bi[cb + lq * 4];
        a0[0] = b4.x; a0[1] = b4.y; a0[2] = b4.z; a0[3] = b4.w;
    }

    const int kbase = kh ? 384 : 0;
    #pragma unroll 6
    for (int c = 0; c < 12; ++c) {
        const int k = kbase + c * 32 + lq * 8;
        float4 xa = *(const float4*)&xp[k];
        float4 xb = *(const float4*)&xp[k + 4];
        float4 wa = *(const float4*)&wp[k];
        float4 wb = *(const float4*)&wp[k + 4];
        bf16x8 ah, al, bh, bl;
        SPLIT8(xa, xb, ah, al)
        SPLIT8(wa, wb, bh, bl)
        a0 = MFMA(bh, ah, a0);     // Wh . xh
        a1 = MFMA(bh, al, a1);     // Wh . xl
        a2 = MFMA(bl, ah, a2);     // Wl . xh
    }
    if (kh) {   // tail k = 768..783 (valid lq<2)
        float4 z4 = make_float4(0.f, 0.f, 0.f, 0.f);
        float4 xa = z4, xb = z4, wa = z4, wb = z4;
        if (lq < 2) {
            const int k = 768 + lq * 8;
            xa = *(const float4*)&xp[k];
            xb = *(const float4*)&xp[k + 4];
            wa = *(const float4*)&wp[k];
            wb = *(const float4*)&wp[k + 4];
        }
        bf16x8 ah, al, bh, bl;
        SPLIT8(xa, xb, ah, al)
        SPLIT8(wa, wb, bh, bl)
        a0 = MFMA(bh, ah, a0);
        a1 = MFMA(bh, al, a1);
        a2 = MFMA(bl, ah, a2);
    }

    f32x4 r;
    #pragma unroll
    for (int i = 0; i < 4; ++i) r[i] = a0[i] + a1[i] + a2[i];

    if (kh) redS[ct][lane] = r;
    __syncthreads();
    if (!kh) {
        f32x4 o = redS[ct][lane];
        float4 st;
        st.x = r[0] + o[0]; st.y = r[1] + o[1];
        st.z = r[2] + o[2]; st.w = r[3] + o[3];
        *(float4*)&zA[(long)(r0 + l15) * U + cb + lq * 4] = st;
    }
}

// ---------------------------------------------------------------------------
// k_picard: EXACT R19/R23 structure (best measured) -- 4 waves x 2 col-tiles,
// 3-term W in registers, bf16-hi LDS ping-pong, rcp-tanh, final z hi+lo ->
// 3-term output GEMM on wave 0. NIT = 6.
// LDS z: byte(r,c) = r*256 + ((2c) ^ ((r&7)<<4))  XOR swizzle.
// ---------------------------------------------------------------------------
__global__ __launch_bounds__(256) void k_picard(
        const float* __restrict__ zA, const float* __restrict__ Wb,
        const float* __restrict__ Wo, const float* __restrict__ bo,
        float* __restrict__ Out, int L) {
    __shared__ unsigned short zhS[2][16 * U];   // 2 x 4 KB

    const int tid  = threadIdx.x;
    const int w    = tid >> 6;          // 0..3
    const int lane = tid & 63;
    const int l15  = lane & 15;
    const int lq   = lane >> 4;
    const int r0   = blockIdx.x * 16;

    float xf[8], zr[8];
    {
        const float* zrow = &zA[(long)(r0 + l15) * U + w * 32 + lq * 4];
        float4 x40 = *(const float4*)&zrow[0];
        float4 x41 = *(const float4*)&zrow[16];
        xf[0] = x40.x; xf[1] = x40.y; xf[2] = x40.z; xf[3] = x40.w;
        xf[4] = x41.x; xf[5] = x41.y; xf[6] = x41.z; xf[7] = x41.w;
    }

    const int swz = (l15 & 7) << 4;
    int offA[4];
    #pragma unroll
    for (int ks = 0; ks < 4; ++ks)
        offA[ks] = l15 * 256 + ((64 * ks + 16 * lq) ^ swz);
    const int offW0 = l15 * 256 + (((64 * w + 8 * lq)) ^ swz);
    const int offW1 = l15 * 256 + (((64 * w + 32 + 8 * lq)) ^ swz);

    char* zhB = (char*)&zhS[0][0];

    for (int l = 0; l < L; ++l) {
        bf16x8 whf[2][4], wlf[2][4];
        #pragma unroll
        for (int ct = 0; ct < 2; ++ct) {
            const int colA = w * 32 + ct * 16 + l15;
            const float* wrow = &Wb[((long)l * U + colA) * U];
            #pragma unroll
            for (int ks = 0; ks < 4; ++ks) {
                const int k = ks * 32 + lq * 8;
                float4 p = *(const float4*)&wrow[k];
                float4 q = *(const float4*)&wrow[k + 4];
                SPLIT8(p, q, whf[ct][ks], wlf[ct][ks])
            }
        }

        {
            uint2 h0, h1;
            #pragma unroll
            for (int i = 0; i < 8; ++i) zr[i] = tanh_fast(xf[i]);
            h0.x = packrn(zr[0], zr[1]); h0.y = packrn(zr[2], zr[3]);
            h1.x = packrn(zr[4], zr[5]); h1.y = packrn(zr[6], zr[7]);
            *(uint2*)(zhB + offW0) = h0;
            *(uint2*)(zhB + offW1) = h1;
        }
        __syncthreads();

        #pragma unroll 2
        for (int it = 0; it < NIT; ++it) {
            const int cur = it & 1;
            const int nxt = cur ^ 1;
            bf16x8 zhf[4];
            #pragma unroll
            for (int ks = 0; ks < 4; ++ks)
                zhf[ks] = *(const bf16x8*)(zhB + cur * 4096 + offA[ks]);

            f32x4 A0 = {xf[0], xf[1], xf[2], xf[3]};
            f32x4 Z4 = {0.f, 0.f, 0.f, 0.f};
            f32x4 A1 = Z4, A2 = Z4, A3 = Z4;
            f32x4 B0 = {xf[4], xf[5], xf[6], xf[7]};
            f32x4 B1 = Z4, B2 = Z4, B3 = Z4;
            A0 = MFMA(whf[0][0], zhf[0], A0);
            B0 = MFMA(whf[1][0], zhf[0], B0);
            A1 = MFMA(whf[0][2], zhf[2], A1);
            B1 = MFMA(whf[1][2], zhf[2], B1);
            A2 = MFMA(wlf[0][0], zhf[0], A2);
            B2 = MFMA(wlf[1][0], zhf[0], B2);
            A3 = MFMA(wlf[0][2], zhf[2], A3);
            B3 = MFMA(wlf[1][2], zhf[2], B3);
            A0 = MFMA(whf[0][1], zhf[1], A0);
            B0 = MFMA(whf[1][1], zhf[1], B0);
            A1 = MFMA(whf[0][3], zhf[3], A1);
            B1 = MFMA(whf[1][3], zhf[3], B1);
            A2 = MFMA(wlf[0][1], zhf[1], A2);
            B2 = MFMA(wlf[1][1], zhf[1], B2);
            A3 = MFMA(wlf[0][3], zhf[3], A3);
            B3 = MFMA(wlf[1][3], zhf[3], B3);

            #pragma unroll
            for (int i = 0; i < 4; ++i) {
                zr[i]     = tanh_fast(A0[i] + A1[i] + A2[i] + A3[i]);
                zr[4 + i] = tanh_fast(B0[i] + B1[i] + B2[i] + B3[i]);
            }
            uint2 h0, h1;
            h0.x = packrn(zr[0], zr[1]); h0.y = packrn(zr[2], zr[3]);
            h1.x = packrn(zr[4], zr[5]); h1.y = packrn(zr[6], zr[7]);
            *(uint2*)(zhB + nxt * 4096 + offW0) = h0;
            *(uint2*)(zhB + nxt * 4096 + offW1) = h1;
            __syncthreads();
        }
        #pragma unroll
        for (int i = 0; i < 8; ++i) xf[i] = zr[i];
    }
    // NIT even => final z hi in buffer 0; z_lo -> buffer 1 (3-term phase 3)
    {
        uint2 l0, l1;
        l0.x = packrn(zr[0] - fromhi((unsigned short)(packrn(zr[0], zr[0]))),
                      zr[1] - fromhi((unsigned short)(packrn(zr[1], zr[1]))));
        l0.y = packrn(zr[2] - fromhi((unsigned short)(packrn(zr[2], zr[2]))),
                      zr[3] - fromhi((unsigned short)(packrn(zr[3], zr[3]))));
        l1.x = packrn(zr[4] - fromhi((unsigned short)(packrn(zr[4], zr[4]))),
                      zr[5] - fromhi((unsigned short)(packrn(zr[5], zr[5]))));
        l1.y = packrn(zr[6] - fromhi((unsigned short)(packrn(zr[6], zr[6]))),
                      zr[7] - fromhi((unsigned short)(packrn(zr[7], zr[7]))));
        *(uint2*)(zhB + 4096 + offW0) = l0;
        *(uint2*)(zhB + 4096 + offW1) = l1;
    }
    __syncthreads();

    if (w == 0) {
        bf16x8 woh[4], wol[4];
        #pragma unroll
        for (int ks = 0; ks < 4; ++ks) {
            float4 p = make_float4(0.f, 0.f, 0.f, 0.f), q = p;
            if (l15 < 10) {
                const float* worow = &Wo[l15 * U + ks * 32 + lq * 8];
                p = *(const float4*)&worow[0];
                q = *(const float4*)&worow[4];
            }
            SPLIT8(p, q, woh[ks], wol[ks])
        }
        bf16x8 zf[4], zl[4];
        #pragma unroll
        for (int ks = 0; ks < 4; ++ks) {
            zf[ks] = *(const bf16x8*)(zhB + offA[ks]);
            zl[ks] = *(const bf16x8*)(zhB + 4096 + offA[ks]);
        }

        f32x4 d0 = {0.f, 0.f, 0.f, 0.f};
        f32x4 d1 = d0, d2 = d0;
        #pragma unroll
        for (int ks = 0; ks < 4; ++ks) {
            d0 = MFMA(woh[ks], zf[ks], d0);
            d1 = MFMA(wol[ks], zf[ks], d1);
            d2 = MFMA(woh[ks], zl[ks], d2);
        }
        float lg[4];
        #pragma unroll
        for (int i = 0; i < 4; ++i) {
            const int c = 4 * lq + i;
            lg[i] = (c < 10) ? (d0[i] + d1[i] + d2[i] + bo[c]) : -1e30f;
        }
        float m = fmaxf(fmaxf(lg[0], lg[1]), fmaxf(lg[2], lg[3]));
        m = fmaxf(m, __shfl_xor(m, 16));
        m = fmaxf(m, __shfl_xor(m, 32));
        float e[4], s = 0.f;
        #pragma unroll
        for (int i = 0; i < 4; ++i) { e[i] = __expf(lg[i] - m); s += e[i]; }
        s += __shfl_xor(s, 16);
        s += __shfl_xor(s, 32);
        const float inv = rcp_fast(s);
        const float inv2 = inv * (2.0f - s * inv);
        #pragma unroll
        for (int i = 0; i < 4; ++i) {
            const int c = 4 * lq + i;
            if (c < 10) Out[(long)(r0 + l15) * 10 + c] = e[i] * inv2;
        }
    }
}

// ---------------------------------------------------------------------------
extern "C" void kernel_launch(void* const* d_in, const int* in_sizes, int n_in,
                              void* d_out, int out_size, void* d_ws, size_t ws_size,
                              hipStream_t stream) {
    const float* x  = (const float*)d_in[0];   // [B,784]
    const float* Wi = (const float*)d_in[1];   // [128,784]
    const float* bi = (const float*)d_in[2];   // [128]
    const float* Wb = (const float*)d_in[3];   // [L,128,128]
    const float* Wo = (const float*)d_in[4];   // [10,128]
    const float* bo = (const float*)d_in[5];   // [10]
    float* out = (float*)d_out;

    const int DIN = 784;
    const int B   = in_sizes[0] / DIN;             // 2048
    const int L   = in_sizes[3] / (U * U);         // 2

    float* zA = (float*)d_ws;                      // [B,U] f32

    k_gemm_in<<<256, 512, 0, stream>>>(x, Wi, bi, zA);
    k_picard<<<B / 16, 256, 0, stream>>>(zA, Wb, Wo, bo, out, L);
}